// Round 12
// baseline (176.615 us; speedup 1.0000x reference)
//
#include <hip/hip_runtime.h>

#define D 128
#define BSHIFT 5                 // 32 rows per bucket
#define BCAP 1024                // entries/bucket; mean 512, +16 sigma
#define EPB_A 1024               // edges per pass-A block (4 contiguous/thread)

typedef unsigned short ushort_t;
typedef unsigned int uint_t;
typedef __attribute__((ext_vector_type(8))) short short8_t;   // 8 bf16 = 4 VGPR
typedef __attribute__((ext_vector_type(4))) float f32x4_t;    // mfma C/D
typedef __attribute__((ext_vector_type(4))) uint_t uint4_t;   // asm ds_read dst
typedef const __attribute__((address_space(1))) void* gas_cptr;
typedef __attribute__((address_space(3))) void* las_ptr;
typedef const __attribute__((address_space(3))) ushort_t* las_cushort;

// ---- edge-index dtype probe (int64 vs int32), wave-uniform, ~free ----
__device__ __forceinline__ bool eidx_is64(const int* eidx) {
    int lane = threadIdx.x & 63;
    int probe = eidx[2 * lane + 1];              // L2-hit after first wave
    return __ballot(probe != 0) == 0ULL;         // int64 high halves all zero
}

__device__ __forceinline__ uint_t f2bf(float f) {
    union { float f; uint_t i; } v; v.f = f;
    return (v.i + 0x7fffu + ((v.i >> 16) & 1u)) >> 16;   // RNE
}
__device__ __forceinline__ float bf_lo(uint_t w) {
    union { uint_t i; float f; } v; v.i = w << 16; return v.f;
}
__device__ __forceinline__ float bf_hi(uint_t w) {
    union { uint_t i; float f; } v; v.i = w & 0xffff0000u; return v.f;
}

// ==== Kernel 1: bucketA + fp32->bf16 conv of x AND W (all independent) ====
// Ledger (R9/R10): fixed harness overhead ~66 us; kernel work ~90 us conserved
// since R4. bucketA blocks are the makespan poles -> EPB_A 1024 (782 blocks,
// 4 contiguous edges/thread, int4 reads). R11 was an infra failure (no
// artifact); this is the same kernel resubmitted to keep the ledger clean.
__global__ __launch_bounds__(256) void pre_kernel(
    const int* __restrict__ eidx, int* __restrict__ gcur,
    int* __restrict__ bucket, int E, int NBUK, int ab,
    const float* __restrict__ x, uint_t* __restrict__ xb, int total8, int cvb,
    const float* __restrict__ Wsrc, uint_t* __restrict__ wb, int N) {
    int t = threadIdx.x;

    if ((int)blockIdx.x >= ab) {                 // ---- conv roles ----
        if (xb == nullptr) return;
        int cb = blockIdx.x - ab;
        if (cb < cvb) {                          // x conversion
            int i = cb * 256 + t;
            if (i < total8) {                    // one thread = 8 elems
                const float4* p = (const float4*)(x + (size_t)i * 8);
                float4 a = p[0], b = p[1];
                uint4 o;
                o.x = f2bf(a.x) | (f2bf(a.y) << 16);
                o.y = f2bf(a.z) | (f2bf(a.w) << 16);
                o.z = f2bf(b.x) | (f2bf(b.y) << 16);
                o.w = f2bf(b.z) | (f2bf(b.w) << 16);
                *(uint4*)(xb + (size_t)i * 4) = o;
            }
            if (cb == 0 && t < 16) {
                // dummy zero row at index N: xb is uint_t* here, row N starts
                // at uint offset N*(D/2) (byte N*256).
                uint4 z; z.x = 0u; z.y = 0u; z.z = 0u; z.w = 0u;
                ((uint4*)(xb + (size_t)N * (D / 2)))[t] = z;
            }
        } else {                                 // W conversion (D*D/8 = 2048 items)
            int i = (cb - cvb) * 256 + t;
            if (i < D * D / 8) {
                const float4* p = (const float4*)(Wsrc + (size_t)i * 8);
                float4 a = p[0], b = p[1];
                uint4 o;
                o.x = f2bf(a.x) | (f2bf(a.y) << 16);
                o.y = f2bf(a.z) | (f2bf(a.w) << 16);
                o.z = f2bf(b.x) | (f2bf(b.y) << 16);
                o.w = f2bf(b.z) | (f2bf(b.w) << 16);
                *(uint4*)(wb + (size_t)i * 4) = o;
            }
        }
        return;
    }

    // ---- bucketA role: coarse-bucket edges, contiguous vector reads ----
    __shared__ int lhist[2048];   // supports N <= 65536 at 32 rows/bucket
    __shared__ int lbase[2048];
    bool is64 = eidx_is64(eidx);
    for (int i = t; i < NBUK; i += 256) lhist[i] = 0;
    __syncthreads();

    int e0 = blockIdx.x * EPB_A;
    int e1 = min(e0 + EPB_A, E);
    int base = e0 + 4 * t;                    // 4 contiguous edges per thread
    int rr[4], cc[4];
    #pragma unroll
    for (int k = 0; k < 4; ++k) rr[k] = -1;
    if (is64) {
        if (base + 4 <= e1 && (E & 1) == 0) { // int4-aligned fast path
            const int4* rp = (const int4*)(eidx + 2 * (size_t)base);
            const int4* cp = (const int4*)(eidx + 2 * (size_t)E + 2 * (size_t)base);
            #pragma unroll
            for (int g = 0; g < 2; ++g) {
                int4 r = rp[g], c = cp[g];
                rr[2 * g]     = r.x; cc[2 * g]     = c.x;
                rr[2 * g + 1] = r.z; cc[2 * g + 1] = c.z;
            }
        } else {
            #pragma unroll
            for (int k = 0; k < 4; ++k) {
                int e = base + k;
                if (e < e1) { rr[k] = eidx[2 * e]; cc[k] = eidx[2 * E + 2 * e]; }
            }
        }
    } else {
        if (base + 4 <= e1 && (E & 3) == 0) { // int4-aligned fast path
            int4 r0 = *(const int4*)(eidx + base);
            int4 c0 = *(const int4*)(eidx + (size_t)E + base);
            rr[0] = r0.x; rr[1] = r0.y; rr[2] = r0.z; rr[3] = r0.w;
            cc[0] = c0.x; cc[1] = c0.y; cc[2] = c0.z; cc[3] = c0.w;
        } else {
            #pragma unroll
            for (int k = 0; k < 4; ++k) {
                int e = base + k;
                if (e < e1) { rr[k] = eidx[e]; cc[k] = eidx[E + e]; }
            }
        }
    }
    #pragma unroll
    for (int k = 0; k < 4; ++k)
        if (rr[k] >= 0) atomicAdd(&lhist[rr[k] >> BSHIFT], 1);
    __syncthreads();
    for (int i = t; i < NBUK; i += 256) {
        int h = lhist[i];
        lbase[i] = (h > 0) ? atomicAdd(&gcur[i], h) : 0;
        lhist[i] = 0;
    }
    __syncthreads();
    #pragma unroll
    for (int k = 0; k < 4; ++k) {             // scatter from regs (no re-read)
        if (rr[k] >= 0) {
            int b = rr[k] >> BSHIFT;
            int p = atomicAdd(&lhist[b], 1);   // LDS: cheap
            int idx = lbase[b] + p;
            if (idx < BCAP) bucket[b * BCAP + idx] = ((rr[k] & 31) << 24) | cc[k];
        }
    }
}

// ==== Kernel 2: FUSED bucketB (LDS) + 2-deep global_load_lds + MFMA ====
// R10 refuted depth-3 (58.4 us: LDS 63 KB cut occupancy 3->2 blocks/CU, and
// the gather is random-line-HBM-service-bound, not depth-bound). Revert to
// the R7-proven 2-deep / 46.5 KB / (256,3) pipeline; KEEP R10's step-1
// single-pass reg-read of bucket entries (4 x int4/thread = BCAP).
#define ISSUE(c, bufsel)                                                      \
    {                                                                         \
        ushort_t* db_ = wstage + (bufsel) * 2048;                             \
        __builtin_amdgcn_global_load_lds(                                     \
            (gas_cptr)(xb + (size_t)(c).x * D + 8 * sl),                      \
            (las_ptr)(db_), 16, 0, 0);                                        \
        __builtin_amdgcn_global_load_lds(                                     \
            (gas_cptr)(xb + (size_t)(c).y * D + 8 * sl),                      \
            (las_ptr)(db_ + 512), 16, 0, 0);                                  \
        __builtin_amdgcn_global_load_lds(                                     \
            (gas_cptr)(xb + (size_t)(c).z * D + 8 * sl),                      \
            (las_ptr)(db_ + 1024), 16, 0, 0);                                 \
        __builtin_amdgcn_global_load_lds(                                     \
            (gas_cptr)(xb + (size_t)(c).w * D + 8 * sl),                      \
            (las_ptr)(db_ + 1536), 16, 0, 0);                                 \
    }

#define ACCV(v)                                                               \
    a0 += bf_lo((v)[0]); a1 += bf_hi((v)[0]);                                 \
    a2 += bf_lo((v)[1]); a3 += bf_hi((v)[1]);                                 \
    a4 += bf_lo((v)[2]); a5 += bf_hi((v)[2]);                                 \
    a6 += bf_lo((v)[3]); a7 += bf_hi((v)[3]);

// consume one 4-edge batch via inline-asm ds_read (invisible to the compiler
// vmcnt legalizer -- R6 lesson: visible LDS reads get s_waitcnt vmcnt(0))
#define CONSUME                                                               \
    {                                                                         \
        uint4_t v0, v1, v2, v3;                                               \
        asm volatile("ds_read_b128 %0, %1"             : "=v"(v0) : "v"(sbp));\
        asm volatile("ds_read_b128 %0, %1 offset:1024" : "=v"(v1) : "v"(sbp));\
        asm volatile("ds_read_b128 %0, %1 offset:2048" : "=v"(v2) : "v"(sbp));\
        asm volatile("ds_read_b128 %0, %1 offset:3072" : "=v"(v3) : "v"(sbp));\
        asm volatile("s_waitcnt lgkmcnt(0)" ::: "memory");                    \
        __builtin_amdgcn_sched_barrier(0);                                    \
        ACCV(v0) ACCV(v1) ACCV(v2) ACCV(v3)                                   \
    }

__global__ __launch_bounds__(256, 3) void fused_bf_kernel(
    const ushort_t* __restrict__ xb, const int* __restrict__ gcur,
    const int* __restrict__ bucket, const ushort_t* __restrict__ Wb,
    const float* __restrict__ bias, float* __restrict__ out, int N) {
    __shared__ alignas(16) int sE[1152];          // 4.5 KiB packed 4-padded list
    __shared__ int lcnt[32], lpos[32], lstart[32];
    __shared__ alignas(16) ushort_t sA[32 * 136]; // 8.5 KiB [n][k] bf16 +pad
    __shared__ alignas(16) ushort_t stage[16384]; // 32 KiB 4 waves x 2 x 4 KB
    int t = threadIdx.x;
    int b = blockIdx.x;

    // ---- step 1: bucketB in LDS (bucket entries read ONCE into regs) ----
    if (t < 32) { lcnt[t] = 0; lpos[t] = 0; }
    __syncthreads();
    int tot = min(gcur[b], BCAP);
    const int* bp = bucket + (size_t)b * BCAP;
    int4 ev = make_int4(-1, -1, -1, -1);          // entries >= 0; -1 = invalid
    if (4 * t + 3 < tot) {
        ev = *(const int4*)(bp + 4 * t);
    } else {
        if (4 * t + 0 < tot) ev.x = bp[4 * t + 0];
        if (4 * t + 1 < tot) ev.y = bp[4 * t + 1];
        if (4 * t + 2 < tot) ev.z = bp[4 * t + 2];
        if (4 * t + 3 < tot) ev.w = bp[4 * t + 3];
    }
    if (ev.x >= 0) atomicAdd(&lcnt[ev.x >> 24], 1);
    if (ev.y >= 0) atomicAdd(&lcnt[ev.y >> 24], 1);
    if (ev.z >= 0) atomicAdd(&lcnt[ev.z >> 24], 1);
    if (ev.w >= 0) atomicAdd(&lcnt[ev.w >> 24], 1);
    __syncthreads();
    if (t == 0) {
        int run = 0;
        #pragma unroll
        for (int i = 0; i < 32; ++i) {
            lstart[i] = run;
            run += (lcnt[i] + 3) & ~3;     // 4-aligned, 4-padded segments
        }                                  // run <= 1024 + 32*3 = 1120 < 1152
    }
    __syncthreads();
    {
        int v[4] = { ev.x, ev.y, ev.z, ev.w };
        #pragma unroll
        for (int q = 0; q < 4; ++q) {
            if (v[q] >= 0) {
                int rl = v[q] >> 24;
                int p = atomicAdd(&lpos[rl], 1);
                int idx = lstart[rl] + p;
                if (idx < 1152) sE[idx] = v[q] & 0xFFFFFF;
            }
        }
    }
    if (t < 32) {                          // pad with dummy (zero) row index N
        int c0 = lcnt[t];
        int pe = (c0 + 3) & ~3;
        for (int p = c0; p < pe; ++p) {
            int idx = lstart[t] + p;
            if (idx < 1152) sE[idx] = N;
        }
    }
    __syncthreads();

    // ---- step 2: gather means -> bf16 LDS A-tile (2-deep staging) ----
    int lane = t & 63, wave = t >> 6;
    int qi = t >> 4, sl = t & 15;          // quarter [0,16), sublane [0,16)
    int nbase = b << BSHIFT;               // 32 rows per block
    ushort_t* wstage = stage + (wave << 12);   // 8 KB (4096 ushorts) per wave

    #pragma unroll
    for (int quad = 0; quad < 2; ++quad) {
        int n = 2 * qi + quad;             // row within bucket [0,32)
        int nr = lcnt[n];
        int st = lstart[n];                // 4-aligned
        int trips = ((nr + 3) & ~3) >> 2;  // 4-edge batches
        int wmax = trips;                  // wave-uniform trip count
        wmax = max(wmax, __shfl_xor(wmax, 16));
        wmax = max(wmax, __shfl_xor(wmax, 32));
        float a0 = 0.f, a1 = 0.f, a2 = 0.f, a3 = 0.f;
        float a4 = 0.f, a5 = 0.f, a6 = 0.f, a7 = 0.f;
        if (wmax > 0) {
            int4 cc0 = (0 < trips) ? *(const int4*)(sE + st)
                                   : make_int4(N, N, N, N);
            ISSUE(cc0, 0)
            __builtin_amdgcn_sched_barrier(0);
            for (int bt = 0; bt < wmax; ++bt) {
                int buf = bt & 1;
                if (bt + 1 < wmax) {       // wave-uniform branch
                    int4 cn = (bt + 1 < trips)
                        ? *(const int4*)(sE + st + 4 * (bt + 1))
                        : make_int4(N, N, N, N);
                    ISSUE(cn, buf ^ 1)
                    __builtin_amdgcn_sched_barrier(0);
                    asm volatile("s_waitcnt vmcnt(4)" ::: "memory");
                } else {
                    asm volatile("s_waitcnt vmcnt(0)" ::: "memory");
                }
                __builtin_amdgcn_sched_barrier(0);
                las_cushort sbp = (las_cushort)(wstage + buf * 2048 + lane * 8);
                CONSUME
            }
        }
        float inv = (nr > 0) ? 1.0f / (float)nr : 0.0f;
        uint4 pk;
        pk.x = f2bf(a0 * inv) | (f2bf(a1 * inv) << 16);
        pk.y = f2bf(a2 * inv) | (f2bf(a3 * inv) << 16);
        pk.z = f2bf(a4 * inv) | (f2bf(a5 * inv) << 16);
        pk.w = f2bf(a6 * inv) | (f2bf(a7 * inv) << 16);
        *(uint4*)(sA + n * 136 + 8 * sl) = pk;
    }
    __syncthreads();

    // ---- step 3: out[n][j] = mean[n][:] . W[j][:] + b[j]  via MFMA ----
    // 4 waves: rt = wave&1 (2 row-tiles of 16), jgrp = wave>>1 (4 j-tiles).
    // A-frag: lane holds A[l&15][(l>>4)*8 + e];  B = W^T so lane reads
    // W[j = jt*16 + (l&15)][k .. k+7] -- contiguous global bf16.
    {
        int rt = wave & 1, jgrp = wave >> 1;
        int ml = lane & 15, kh = lane >> 4;
        short8_t afr[4];
        #pragma unroll
        for (int ks = 0; ks < 4; ++ks)
            afr[ks] = *(const short8_t*)(sA + (rt * 16 + ml) * 136 + ks * 32 + kh * 8);
        f32x4_t acc[4];
        #pragma unroll
        for (int q = 0; q < 4; ++q) acc[q] = (f32x4_t){0.f, 0.f, 0.f, 0.f};
        #pragma unroll
        for (int q = 0; q < 4; ++q) {
            int j = (jgrp * 4 + q) * 16 + ml;
            #pragma unroll
            for (int ks = 0; ks < 4; ++ks) {
                short8_t bfr = *(const short8_t*)(Wb + (size_t)j * D + ks * 32 + kh * 8);
                acc[q] = __builtin_amdgcn_mfma_f32_16x16x32_bf16(afr[ks], bfr, acc[q], 0, 0, 0);
            }
        }
        // C/D layout: col = lane&15 (j), row = (lane>>4)*4 + reg (n)
        #pragma unroll
        for (int q = 0; q < 4; ++q) {
            int j = (jgrp * 4 + q) * 16 + ml;
            float bj = bias[j];
            #pragma unroll
            for (int r = 0; r < 4; ++r) {
                int gn = nbase + rt * 16 + kh * 4 + r;
                if (gn < N) out[(size_t)gn * D + j] = acc[q][r] + bj;
            }
        }
    }
}

// ---- fallback Pass B: bucket -> packed global elist (fp32 path only) ----
__global__ __launch_bounds__(256) void prep_kernel(
    const int* __restrict__ gcur, const int* __restrict__ bucket,
    int* __restrict__ elist, int* __restrict__ cnt,
    int* __restrict__ start, int N, int NBUK) {
    __shared__ int lcnt[32], lpos[32], lstart[32];
    int t = threadIdx.x;
    int b = blockIdx.x;
    if (t < 32) { lcnt[t] = 0; lpos[t] = 0; }
    __syncthreads();
    int tot = min(gcur[b], BCAP);
    const int* bp = bucket + (size_t)b * BCAP;
    for (int i = t; i < tot; i += 256)
        atomicAdd(&lcnt[bp[i] >> 24], 1);
    __syncthreads();
    if (t == 0) {
        int run = 0;
        #pragma unroll
        for (int i = 0; i < 32; ++i) {
            lstart[i] = run;
            run += (lcnt[i] + 3) & ~3;     // 4-aligned segments
        }
    }
    __syncthreads();
    for (int i = t; i < tot; i += 256) {
        int v = bp[i];
        int rl = v >> 24;
        int p = atomicAdd(&lpos[rl], 1);
        int idx = lstart[rl] + p;
        if (idx < BCAP) elist[(size_t)b * BCAP + idx] = v & 0xFFFFFF;
    }
    if (t < 32) {
        int gr = (b << BSHIFT) + t;
        if (gr < N) { cnt[gr] = lcnt[t]; start[gr] = b * BCAP + lstart[t]; }
    }
}

// ---- fp32 fused variant (proven; used when ws can't hold xb).
// Reads only i < cnt entries. ----
__global__ __launch_bounds__(256, 6) void fused_kernel(
    const float* __restrict__ x, const int* __restrict__ elist,
    const int* __restrict__ cnt, const int* __restrict__ start,
    const float* __restrict__ W, const float* __restrict__ bias,
    float* __restrict__ out, int N) {
    __shared__ float sT[128 * 36];
    __shared__ float wc[16 * 132];
    int t = threadIdx.x;
    int lane = t & 63, wave = t >> 6;
    int half = lane >> 5, sl = lane & 31;
    int nbase = blockIdx.x * 32;

    #pragma unroll
    for (int pair = 0; pair < 4; ++pair) {
        int n = wave * 8 + pair * 2 + half;
        int gn = nbase + n;
        int nr  = (gn < N) ? cnt[gn]   : 0;
        int beg = (gn < N) ? start[gn] : 0;
        int nro  = __shfl(nr, lane ^ 32);
        int both = min(nr, nro);
        float ax = 0.f, ay = 0.f, az = 0.f, aw = 0.f;
        int i = 0;
        for (; i + 8 <= both; i += 8) {
            int4 cA = *(const int4*)(elist + beg + i);
            int4 cB = *(const int4*)(elist + beg + i + 4);
            float4 v0 = *(const float4*)(x + (size_t)cA.x * D + 4 * sl);
            float4 v1 = *(const float4*)(x + (size_t)cA.y * D + 4 * sl);
            float4 v2 = *(const float4*)(x + (size_t)cA.z * D + 4 * sl);
            float4 v3 = *(const float4*)(x + (size_t)cA.w * D + 4 * sl);
            float4 v4 = *(const float4*)(x + (size_t)cB.x * D + 4 * sl);
            float4 v5 = *(const float4*)(x + (size_t)cB.y * D + 4 * sl);
            float4 v6 = *(const float4*)(x + (size_t)cB.z * D + 4 * sl);
            float4 v7 = *(const float4*)(x + (size_t)cB.w * D + 4 * sl);
            ax += ((v0.x + v1.x) + (v2.x + v3.x)) + ((v4.x + v5.x) + (v6.x + v7.x));
            ay += ((v0.y + v1.y) + (v2.y + v3.y)) + ((v4.y + v5.y) + (v6.y + v7.y));
            az += ((v0.z + v1.z) + (v2.z + v3.z)) + ((v4.z + v5.z) + (v6.z + v7.z));
            aw += ((v0.w + v1.w) + (v2.w + v3.w)) + ((v4.w + v5.w) + (v6.w + v7.w));
        }
        for (; i < nr; ++i) {
            int c0 = elist[beg + i];
            float4 v = *(const float4*)(x + (size_t)c0 * D + 4 * sl);
            ax += v.x; ay += v.y; az += v.z; aw += v.w;
        }
        float inv = (nr > 0) ? 1.0f / (float)nr : 0.0f;
        int k0 = 4 * sl;
        sT[(k0 + 0) * 36 + n] = ax * inv;
        sT[(k0 + 1) * 36 + n] = ay * inv;
        sT[(k0 + 2) * 36 + n] = az * inv;
        sT[(k0 + 3) * 36 + n] = aw * inv;
    }

    int jg = t & 31, ng = t >> 5;
    int j0 = jg * 4, n0 = ng * 4;
    float acc[4][4] = {};
    for (int kc = 0; kc < 8; ++kc) {
        __syncthreads();
        #pragma unroll
        for (int i = 0; i < 8; ++i) {
            int idx = t + i * 256;
            int j = idx >> 4, kk = idx & 15;
            wc[kk * 132 + j] = W[j * D + kc * 16 + kk];
        }
        __syncthreads();
        #pragma unroll
        for (int kk = 0; kk < 16; ++kk) {
            int k = kc * 16 + kk;
            float4 s4 = *(const float4*)(sT + k * 36 + n0);
            float4 w4 = *(const float4*)(wc + kk * 132 + j0);
            acc[0][0] = fmaf(s4.x, w4.x, acc[0][0]); acc[0][1] = fmaf(s4.x, w4.y, acc[0][1]);
            acc[0][2] = fmaf(s4.x, w4.z, acc[0][2]); acc[0][3] = fmaf(s4.x, w4.w, acc[0][3]);
            acc[1][0] = fmaf(s4.y, w4.x, acc[1][0]); acc[1][1] = fmaf(s4.y, w4.y, acc[1][1]);
            acc[1][2] = fmaf(s4.y, w4.z, acc[1][2]); acc[1][3] = fmaf(s4.y, w4.w, acc[1][3]);
            acc[2][0] = fmaf(s4.z, w4.x, acc[2][0]); acc[2][1] = fmaf(s4.z, w4.y, acc[2][1]);
            acc[2][2] = fmaf(s4.z, w4.z, acc[2][2]); acc[2][3] = fmaf(s4.z, w4.w, acc[2][3]);
            acc[3][0] = fmaf(s4.w, w4.x, acc[3][0]); acc[3][1] = fmaf(s4.w, w4.y, acc[3][1]);
            acc[3][2] = fmaf(s4.w, w4.z, acc[3][2]); acc[3][3] = fmaf(s4.w, w4.w, acc[3][3]);
        }
    }
    float4 b4 = *(const float4*)(bias + j0);
    #pragma unroll
    for (int i = 0; i < 4; ++i) {
        int gn = nbase + n0 + i;
        if (gn >= N) continue;
        float4 o;
        o.x = acc[i][0] + b4.x;
        o.y = acc[i][1] + b4.y;
        o.z = acc[i][2] + b4.z;
        o.w = acc[i][3] + b4.w;
        *(float4*)(out + (size_t)gn * D + j0) = o;
    }
}

// ==== last-resort fallback: atomic scatter + divide + gemm (proven) ====
__global__ __launch_bounds__(256) void scatter_kernel(
    const float* __restrict__ x, const int* __restrict__ eidx,
    float* summed, float* __restrict__ counts, int E) {
    int t = blockIdx.x * 256 + threadIdx.x;
    int lane = threadIdx.x & 63;
    bool is64 = eidx_is64(eidx);
    int e = t >> 6;
    if (e >= E) return;
    int d = lane * 2;
    int r, c;
    if (is64) { r = eidx[2 * e]; c = eidx[2 * E + 2 * e]; }
    else      { r = eidx[e];     c = eidx[E + e]; }
    float2 v = *(const float2*)(x + (size_t)c * D + d);
    float* dst = summed + (size_t)r * D + d;
    atomicAdd(dst, v.x);
    atomicAdd(dst + 1, v.y);
    if (lane == 0) atomicAdd(counts + r, 1.0f);
}

__global__ __launch_bounds__(256) void divide_kernel(
    float* __restrict__ sums, const float* __restrict__ counts, int N) {
    int g = blockIdx.x * 256 + threadIdx.x;
    int r = g >> 6, lane = g & 63;
    if (r >= N) return;
    float inv = 1.0f / fmaxf(counts[r], 1.0f);
    float2* p = (float2*)(sums + (size_t)r * D + 2 * lane);
    float2 v = *p;
    v.x *= inv; v.y *= inv;
    *p = v;
}

__global__ __launch_bounds__(256) void gemm_kernel(
    float* inout, const float* __restrict__ W,
    const float* __restrict__ bias, int N) {
    __shared__ float sT[128 * 36];
    __shared__ float wc[32 * 132];
    int t = threadIdx.x;
    int nbase = blockIdx.x * 32;
    #pragma unroll
    for (int i = 0; i < 16; ++i) {
        int idx = t + i * 256;
        int n = idx >> 7, k = idx & 127;
        int gn = nbase + n;
        sT[k * 36 + n] = (gn < N) ? inout[(size_t)gn * D + k] : 0.0f;
    }
    int jg = t & 31, ng = t >> 5;
    int j0 = jg * 4, n0 = ng * 4;
    float acc[4][4] = {};
    for (int kc = 0; kc < 4; ++kc) {
        __syncthreads();
        #pragma unroll
        for (int i = 0; i < 16; ++i) {
            int idx = t + i * 256;
            int j = idx >> 5, kk = idx & 31;
            wc[kk * 132 + j] = W[j * D + kc * 32 + kk];
        }
        __syncthreads();
        #pragma unroll 8
        for (int kk = 0; kk < 32; ++kk) {
            int k = kc * 32 + kk;
            float4 s4 = *(const float4*)(sT + k * 36 + n0);
            float4 w4 = *(const float4*)(wc + kk * 132 + j0);
            acc[0][0] = fmaf(s4.x, w4.x, acc[0][0]); acc[0][1] = fmaf(s4.x, w4.y, acc[0][1]);
            acc[0][2] = fmaf(s4.x, w4.z, acc[0][2]); acc[0][3] = fmaf(s4.x, w4.w, acc[0][3]);
            acc[1][0] = fmaf(s4.y, w4.x, acc[1][0]); acc[1][1] = fmaf(s4.y, w4.y, acc[1][1]);
            acc[1][2] = fmaf(s4.y, w4.z, acc[1][2]); acc[1][3] = fmaf(s4.y, w4.w, acc[1][3]);
            acc[2][0] = fmaf(s4.z, w4.x, acc[2][0]); acc[2][1] = fmaf(s4.z, w4.y, acc[2][1]);
            acc[2][2] = fmaf(s4.z, w4.z, acc[2][2]); acc[2][3] = fmaf(s4.z, w4.w, acc[2][3]);
            acc[3][0] = fmaf(s4.w, w4.x, acc[3][0]); acc[3][1] = fmaf(s4.w, w4.y, acc[3][1]);
            acc[3][2] = fmaf(s4.w, w4.z, acc[3][2]); acc[3][3] = fmaf(s4.w, w4.w, acc[3][3]);
        }
    }
    float4 b4 = *(const float4*)(bias + j0);
    #pragma unroll
    for (int i = 0; i < 4; ++i) {
        int gn = nbase + n0 + i;
        if (gn >= N) continue;
        float4 o;
        o.x = acc[i][0] + b4.x;
        o.y = acc[i][1] + b4.y;
        o.z = acc[i][2] + b4.z;
        o.w = acc[i][3] + b4.w;
        *(float4*)(inout + (size_t)gn * D + j0) = o;
    }
}

extern "C" void kernel_launch(void* const* d_in, const int* in_sizes, int n_in,
                              void* d_out, int out_size, void* d_ws, size_t ws_size,
                              hipStream_t stream) {
    // setup_inputs order: x, edge_index, batch_size, num_nodes, W, b
    const float* x = (const float*)d_in[0];
    const int* eidx = (const int*)d_in[1];
    const float* W = (const float*)d_in[4];
    const float* b = (const float*)d_in[5];
    float* out = (float*)d_out;

    int N = in_sizes[0] / D;   // 50000
    int E = in_sizes[1] / 2;   // 800000
    int NBUK = (N + 31) >> BSHIFT;   // 1563
    int ab = (E + EPB_A - 1) / EPB_A;

    // ws layout, 256B-aligned segments (cnt/start/elist used by fallback only).
    size_t o0 = 0;
    size_t o_gc = o0;  o0 += ((size_t)NBUK * 4 + 255) & ~255ULL;
    size_t o_cn = o0;  o0 += ((size_t)N * 4 + 255) & ~255ULL;
    size_t o_st = o0;  o0 += ((size_t)N * 4 + 255) & ~255ULL;
    size_t o_bk = o0;  o0 += (size_t)NBUK * BCAP * 4;
    size_t o_el = o0;  o0 += (size_t)NBUK * BCAP * 4;
    size_t base_need = o0;
    size_t o_xb = o0;  o0 += (((size_t)(N + 1) * D * 2) + 255) & ~255ULL;  // bf16 x + dummy
    size_t o_wb = o0;  size_t bf_need = o0 + (size_t)D * D * 2;            // bf16 W

    bool cap_ok = (N <= 65536) && ((size_t)NBUK * BCAP >= (size_t)E);

    int cvb = (N * D / 8 + 255) / 256;
    int wvb = (D * D / 8 + 255) / 256;   // 8 blocks for W conversion

    if (cap_ok && ws_size >= bf_need) {
        char* ws = (char*)d_ws;
        int*      gcur  = (int*)(ws + o_gc);
        int*      bkt   = (int*)(ws + o_bk);
        ushort_t* xb    = (ushort_t*)(ws + o_xb);
        ushort_t* wb    = (ushort_t*)(ws + o_wb);

        hipMemsetAsync(gcur, 0, (size_t)NBUK * 4, stream);  // 6 KB only
        pre_kernel<<<ab + cvb + wvb, 256, 0, stream>>>(
            eidx, gcur, bkt, E, NBUK, ab,
            x, (uint_t*)xb, N * D / 8, cvb, W, (uint_t*)wb, N);
        fused_bf_kernel<<<NBUK, 256, 0, stream>>>(xb, gcur, bkt, wb, b, out, N);
    } else if (cap_ok && ws_size >= base_need) {
        char* ws = (char*)d_ws;
        int* gcur  = (int*)(ws + o_gc);
        int* cnt   = (int*)(ws + o_cn);
        int* start = (int*)(ws + o_st);
        int* bkt   = (int*)(ws + o_bk);
        int* elist = (int*)(ws + o_el);
        int fb = (N + 31) / 32;

        hipMemsetAsync(gcur, 0, (size_t)NBUK * 4, stream);
        pre_kernel<<<ab, 256, 0, stream>>>(
            eidx, gcur, bkt, E, NBUK, ab,
            nullptr, nullptr, 0, 0, nullptr, nullptr, N);
        prep_kernel<<<NBUK, 256, 0, stream>>>(gcur, bkt, elist, cnt, start, N, NBUK);
        fused_kernel<<<fb, 256, 0, stream>>>(x, elist, cnt, start, W, b, out, N);
    } else {
        float* counts = (float*)d_ws;
        int fb = (N + 31) / 32;
        hipMemsetAsync(d_out, 0, (size_t)N * D * sizeof(float), stream);
        hipMemsetAsync(d_ws, 0, (size_t)N * sizeof(float), stream);
        int sb = (E * 64 + 255) / 256;
        scatter_kernel<<<sb, 256, 0, stream>>>(x, eidx, out, counts, E);
        int db = (N * 64 + 255) / 256;
        divide_kernel<<<db, 256, 0, stream>>>(out, counts, N);
        gemm_kernel<<<fb, 256, 0, stream>>>(out, W, b, N);
    }
}

// Round 13
// 160.992 us; speedup vs baseline: 1.0970x; 1.0970x over previous
//
#include <hip/hip_runtime.h>

#define D 128
#define BSHIFT 5                 // 32 rows per bucket
#define BCAP 1024                // entries/bucket; mean 512, +16 sigma
#define EPB_A 2048               // edges per pass-A block (8 contiguous/thread)
                                 // R12 lesson: 1024 doubled per-block fixed
                                 // reservation cost (+19 us). Keep 2048.

typedef unsigned short ushort_t;
typedef unsigned int uint_t;
typedef __attribute__((ext_vector_type(8))) short short8_t;   // 8 bf16 = 4 VGPR
typedef __attribute__((ext_vector_type(4))) float f32x4_t;    // mfma C/D
typedef __attribute__((ext_vector_type(4))) uint_t uint4_t;   // asm ds_read dst
typedef const __attribute__((address_space(1))) void* gas_cptr;
typedef __attribute__((address_space(3))) void* las_ptr;
typedef const __attribute__((address_space(3))) ushort_t* las_cushort;

// ---- edge-index dtype probe (int64 vs int32), wave-uniform, ~free ----
__device__ __forceinline__ bool eidx_is64(const int* eidx) {
    int lane = threadIdx.x & 63;
    int probe = eidx[2 * lane + 1];              // L2-hit after first wave
    return __ballot(probe != 0) == 0ULL;         // int64 high halves all zero
}

__device__ __forceinline__ uint_t f2bf(float f) {
    union { float f; uint_t i; } v; v.f = f;
    return (v.i + 0x7fffu + ((v.i >> 16) & 1u)) >> 16;   // RNE
}
__device__ __forceinline__ float bf_lo(uint_t w) {
    union { uint_t i; float f; } v; v.i = w << 16; return v.f;
}
__device__ __forceinline__ float bf_hi(uint_t w) {
    union { uint_t i; float f; } v; v.i = w & 0xffff0000u; return v.f;
}

// ==== Kernel 1: bucketA + fp32->bf16 conv of x AND W (all independent) ====
// EPB_A 2048 (391 blocks, 8 contiguous edges/thread, int4 reads — R10's
// vectorized variant, residual-neutral vs R7 scalar).
__global__ __launch_bounds__(256) void pre_kernel(
    const int* __restrict__ eidx, int* __restrict__ gcur,
    int* __restrict__ bucket, int E, int NBUK, int ab,
    const float* __restrict__ x, uint_t* __restrict__ xb, int total8, int cvb,
    const float* __restrict__ Wsrc, uint_t* __restrict__ wb, int N) {
    int t = threadIdx.x;

    if ((int)blockIdx.x >= ab) {                 // ---- conv roles ----
        if (xb == nullptr) return;
        int cb = blockIdx.x - ab;
        if (cb < cvb) {                          // x conversion
            int i = cb * 256 + t;
            if (i < total8) {                    // one thread = 8 elems
                const float4* p = (const float4*)(x + (size_t)i * 8);
                float4 a = p[0], b = p[1];
                uint4 o;
                o.x = f2bf(a.x) | (f2bf(a.y) << 16);
                o.y = f2bf(a.z) | (f2bf(a.w) << 16);
                o.z = f2bf(b.x) | (f2bf(b.y) << 16);
                o.w = f2bf(b.z) | (f2bf(b.w) << 16);
                *(uint4*)(xb + (size_t)i * 4) = o;
            }
            if (cb == 0 && t < 16) {
                // dummy zero row at index N: xb is uint_t* here, row N starts
                // at uint offset N*(D/2) (byte N*256).
                uint4 z; z.x = 0u; z.y = 0u; z.z = 0u; z.w = 0u;
                ((uint4*)(xb + (size_t)N * (D / 2)))[t] = z;
            }
        } else {                                 // W conversion (D*D/8 = 2048 items)
            int i = (cb - cvb) * 256 + t;
            if (i < D * D / 8) {
                const float4* p = (const float4*)(Wsrc + (size_t)i * 8);
                float4 a = p[0], b = p[1];
                uint4 o;
                o.x = f2bf(a.x) | (f2bf(a.y) << 16);
                o.y = f2bf(a.z) | (f2bf(a.w) << 16);
                o.z = f2bf(b.x) | (f2bf(b.y) << 16);
                o.w = f2bf(b.z) | (f2bf(b.w) << 16);
                *(uint4*)(wb + (size_t)i * 4) = o;
            }
        }
        return;
    }

    // ---- bucketA role: coarse-bucket edges, contiguous vector reads ----
    __shared__ int lhist[2048];   // supports N <= 65536 at 32 rows/bucket
    __shared__ int lbase[2048];
    bool is64 = eidx_is64(eidx);
    for (int i = t; i < NBUK; i += 256) lhist[i] = 0;
    __syncthreads();

    int e0 = blockIdx.x * EPB_A;
    int e1 = min(e0 + EPB_A, E);
    int base = e0 + 8 * t;                    // 8 contiguous edges per thread
    int rr[8], cc[8];
    #pragma unroll
    for (int k = 0; k < 8; ++k) rr[k] = -1;
    if (is64) {
        if (base + 8 <= e1 && (E & 1) == 0) { // int4-aligned fast path
            const int4* rp = (const int4*)(eidx + 2 * (size_t)base);
            const int4* cp = (const int4*)(eidx + 2 * (size_t)E + 2 * (size_t)base);
            #pragma unroll
            for (int g = 0; g < 4; ++g) {
                int4 r = rp[g], c = cp[g];
                rr[2 * g]     = r.x; cc[2 * g]     = c.x;
                rr[2 * g + 1] = r.z; cc[2 * g + 1] = c.z;
            }
        } else {
            #pragma unroll
            for (int k = 0; k < 8; ++k) {
                int e = base + k;
                if (e < e1) { rr[k] = eidx[2 * e]; cc[k] = eidx[2 * E + 2 * e]; }
            }
        }
    } else {
        if (base + 8 <= e1 && (E & 3) == 0) { // int4-aligned fast path
            const int4* rp = (const int4*)(eidx + base);
            const int4* cp = (const int4*)(eidx + (size_t)E + base);
            int4 r0 = rp[0], r1 = rp[1], c0 = cp[0], c1 = cp[1];
            rr[0] = r0.x; rr[1] = r0.y; rr[2] = r0.z; rr[3] = r0.w;
            rr[4] = r1.x; rr[5] = r1.y; rr[6] = r1.z; rr[7] = r1.w;
            cc[0] = c0.x; cc[1] = c0.y; cc[2] = c0.z; cc[3] = c0.w;
            cc[4] = c1.x; cc[5] = c1.y; cc[6] = c1.z; cc[7] = c1.w;
        } else {
            #pragma unroll
            for (int k = 0; k < 8; ++k) {
                int e = base + k;
                if (e < e1) { rr[k] = eidx[e]; cc[k] = eidx[E + e]; }
            }
        }
    }
    #pragma unroll
    for (int k = 0; k < 8; ++k)
        if (rr[k] >= 0) atomicAdd(&lhist[rr[k] >> BSHIFT], 1);
    __syncthreads();
    for (int i = t; i < NBUK; i += 256) {
        int h = lhist[i];
        lbase[i] = (h > 0) ? atomicAdd(&gcur[i], h) : 0;
        lhist[i] = 0;
    }
    __syncthreads();
    #pragma unroll
    for (int k = 0; k < 8; ++k) {             // scatter from regs (no re-read)
        if (rr[k] >= 0) {
            int b = rr[k] >> BSHIFT;
            int p = atomicAdd(&lhist[b], 1);   // LDS: cheap
            int idx = lbase[b] + p;
            if (idx < BCAP) bucket[b * BCAP + idx] = ((rr[k] & 31) << 24) | cc[k];
        }
    }
}

// ==== Kernel 2: FUSED bucketB (LDS) + 2-deep global_load_lds + MFMA ====
// NEW (cache-blocking by source): each row's elist segment is counting-sorted
// by column QUARTILE (source row in [0,N/4), [N/4,N/2), ...). Mechanism: the
// 12.8 MB x_bf working set exceeds the 4 MB per-XCD L2 (FETCH 75 MB = 71%
// hit). Rows have ~4 batches ~= 1/quartile and blocks run roughly in
// lockstep, so grid-wide the instantaneous source window shrinks to ~3.2 MB
// -> fits per-XCD L2. Ordering only: no extra padding, gather loop untouched.
#define ISSUE(c, bufsel)                                                      \
    {                                                                         \
        ushort_t* db_ = wstage + (bufsel) * 2048;                             \
        __builtin_amdgcn_global_load_lds(                                     \
            (gas_cptr)(xb + (size_t)(c).x * D + 8 * sl),                      \
            (las_ptr)(db_), 16, 0, 0);                                        \
        __builtin_amdgcn_global_load_lds(                                     \
            (gas_cptr)(xb + (size_t)(c).y * D + 8 * sl),                      \
            (las_ptr)(db_ + 512), 16, 0, 0);                                  \
        __builtin_amdgcn_global_load_lds(                                     \
            (gas_cptr)(xb + (size_t)(c).z * D + 8 * sl),                      \
            (las_ptr)(db_ + 1024), 16, 0, 0);                                 \
        __builtin_amdgcn_global_load_lds(                                     \
            (gas_cptr)(xb + (size_t)(c).w * D + 8 * sl),                      \
            (las_ptr)(db_ + 1536), 16, 0, 0);                                 \
    }

#define ACCV(v)                                                               \
    a0 += bf_lo((v)[0]); a1 += bf_hi((v)[0]);                                 \
    a2 += bf_lo((v)[1]); a3 += bf_hi((v)[1]);                                 \
    a4 += bf_lo((v)[2]); a5 += bf_hi((v)[2]);                                 \
    a6 += bf_lo((v)[3]); a7 += bf_hi((v)[3]);

// consume one 4-edge batch via inline-asm ds_read (invisible to the compiler
// vmcnt legalizer -- R6 lesson: visible LDS reads get s_waitcnt vmcnt(0))
#define CONSUME                                                               \
    {                                                                         \
        uint4_t v0, v1, v2, v3;                                               \
        asm volatile("ds_read_b128 %0, %1"             : "=v"(v0) : "v"(sbp));\
        asm volatile("ds_read_b128 %0, %1 offset:1024" : "=v"(v1) : "v"(sbp));\
        asm volatile("ds_read_b128 %0, %1 offset:2048" : "=v"(v2) : "v"(sbp));\
        asm volatile("ds_read_b128 %0, %1 offset:3072" : "=v"(v3) : "v"(sbp));\
        asm volatile("s_waitcnt lgkmcnt(0)" ::: "memory");                    \
        __builtin_amdgcn_sched_barrier(0);                                    \
        ACCV(v0) ACCV(v1) ACCV(v2) ACCV(v3)                                   \
    }

__global__ __launch_bounds__(256, 3) void fused_bf_kernel(
    const ushort_t* __restrict__ xb, const int* __restrict__ gcur,
    const int* __restrict__ bucket, const ushort_t* __restrict__ Wb,
    const float* __restrict__ bias, float* __restrict__ out, int N) {
    __shared__ alignas(16) int sE[1152];          // 4.5 KiB packed 4-padded list
    __shared__ int lcnt4[128], lpos4[128], lstart4[128];  // [row][quartile]
    __shared__ int lcnt[32], lstart[32];          // per-row totals (gather view)
    __shared__ alignas(16) ushort_t sA[32 * 136]; // 8.5 KiB [n][k] bf16 +pad
    __shared__ alignas(16) ushort_t stage[16384]; // 32 KiB 4 waves x 2 x 4 KB
    int t = threadIdx.x;
    int b = blockIdx.x;
    int h1 = N >> 2, h2 = N >> 1, h3 = (N >> 1) + (N >> 2);  // quartile bounds

    // ---- step 1: bucketB in LDS, counting-sorted by (row, col-quartile) ----
    if (t < 128) { lcnt4[t] = 0; lpos4[t] = 0; }
    __syncthreads();
    int tot = min(gcur[b], BCAP);
    const int* bp = bucket + (size_t)b * BCAP;
    int4 ev = make_int4(-1, -1, -1, -1);          // entries >= 0; -1 = invalid
    if (4 * t + 3 < tot) {
        ev = *(const int4*)(bp + 4 * t);
    } else {
        if (4 * t + 0 < tot) ev.x = bp[4 * t + 0];
        if (4 * t + 1 < tot) ev.y = bp[4 * t + 1];
        if (4 * t + 2 < tot) ev.z = bp[4 * t + 2];
        if (4 * t + 3 < tot) ev.w = bp[4 * t + 3];
    }
    {
        int v[4] = { ev.x, ev.y, ev.z, ev.w };
        #pragma unroll
        for (int q = 0; q < 4; ++q) {
            if (v[q] >= 0) {
                int c  = v[q] & 0xFFFFFF;
                int cq = (c >= h2) ? ((c >= h3) ? 3 : 2) : ((c >= h1) ? 1 : 0);
                atomicAdd(&lcnt4[((v[q] >> 24) << 2) | cq], 1);
            }
        }
    }
    __syncthreads();
    if (t == 0) {
        int run = 0;
        #pragma unroll
        for (int r = 0; r < 32; ++r) {
            lstart[r] = run;
            #pragma unroll
            for (int q = 0; q < 4; ++q) {
                lstart4[(r << 2) | q] = run;
                run += lcnt4[(r << 2) | q];
            }
            int cr = run - lstart[r];
            lcnt[r] = cr;                     // true per-row count
            run += (-cr) & 3;                 // 4-pad the row segment
        }                                     // run <= 1024 + 32*3 = 1120 < 1152
    }
    __syncthreads();
    {
        int v[4] = { ev.x, ev.y, ev.z, ev.w };
        #pragma unroll
        for (int q = 0; q < 4; ++q) {
            if (v[q] >= 0) {
                int c  = v[q] & 0xFFFFFF;
                int cq = (c >= h2) ? ((c >= h3) ? 3 : 2) : ((c >= h1) ? 1 : 0);
                int slot = ((v[q] >> 24) << 2) | cq;
                int p = atomicAdd(&lpos4[slot], 1);
                int idx = lstart4[slot] + p;
                if (idx < 1152) sE[idx] = c;
            }
        }
    }
    if (t < 32) {                          // pad with dummy (zero) row index N
        int c0 = lcnt[t];
        int pe = (c0 + 3) & ~3;
        for (int p = c0; p < pe; ++p) {
            int idx = lstart[t] + p;
            if (idx < 1152) sE[idx] = N;
        }
    }
    __syncthreads();

    // ---- step 2: gather means -> bf16 LDS A-tile (2-deep staging) ----
    int lane = t & 63, wave = t >> 6;
    int qi = t >> 4, sl = t & 15;          // quarter [0,16), sublane [0,16)
    int nbase = b << BSHIFT;               // 32 rows per block
    ushort_t* wstage = stage + (wave << 12);   // 8 KB (4096 ushorts) per wave

    #pragma unroll
    for (int quad = 0; quad < 2; ++quad) {
        int n = 2 * qi + quad;             // row within bucket [0,32)
        int nr = lcnt[n];
        int st = lstart[n];                // 4-aligned
        int trips = ((nr + 3) & ~3) >> 2;  // 4-edge batches
        int wmax = trips;                  // wave-uniform trip count
        wmax = max(wmax, __shfl_xor(wmax, 16));
        wmax = max(wmax, __shfl_xor(wmax, 32));
        float a0 = 0.f, a1 = 0.f, a2 = 0.f, a3 = 0.f;
        float a4 = 0.f, a5 = 0.f, a6 = 0.f, a7 = 0.f;
        if (wmax > 0) {
            int4 cc0 = (0 < trips) ? *(const int4*)(sE + st)
                                   : make_int4(N, N, N, N);
            ISSUE(cc0, 0)
            __builtin_amdgcn_sched_barrier(0);
            for (int bt = 0; bt < wmax; ++bt) {
                int buf = bt & 1;
                if (bt + 1 < wmax) {       // wave-uniform branch
                    int4 cn = (bt + 1 < trips)
                        ? *(const int4*)(sE + st + 4 * (bt + 1))
                        : make_int4(N, N, N, N);
                    ISSUE(cn, buf ^ 1)
                    __builtin_amdgcn_sched_barrier(0);
                    asm volatile("s_waitcnt vmcnt(4)" ::: "memory");
                } else {
                    asm volatile("s_waitcnt vmcnt(0)" ::: "memory");
                }
                __builtin_amdgcn_sched_barrier(0);
                las_cushort sbp = (las_cushort)(wstage + buf * 2048 + lane * 8);
                CONSUME
            }
        }
        float inv = (nr > 0) ? 1.0f / (float)nr : 0.0f;
        uint4 pk;
        pk.x = f2bf(a0 * inv) | (f2bf(a1 * inv) << 16);
        pk.y = f2bf(a2 * inv) | (f2bf(a3 * inv) << 16);
        pk.z = f2bf(a4 * inv) | (f2bf(a5 * inv) << 16);
        pk.w = f2bf(a6 * inv) | (f2bf(a7 * inv) << 16);
        *(uint4*)(sA + n * 136 + 8 * sl) = pk;
    }
    __syncthreads();

    // ---- step 3: out[n][j] = mean[n][:] . W[j][:] + b[j]  via MFMA ----
    // 4 waves: rt = wave&1 (2 row-tiles of 16), jgrp = wave>>1 (4 j-tiles).
    // A-frag: lane holds A[l&15][(l>>4)*8 + e];  B = W^T so lane reads
    // W[j = jt*16 + (l&15)][k .. k+7] -- contiguous global bf16.
    {
        int rt = wave & 1, jgrp = wave >> 1;
        int ml = lane & 15, kh = lane >> 4;
        short8_t afr[4];
        #pragma unroll
        for (int ks = 0; ks < 4; ++ks)
            afr[ks] = *(const short8_t*)(sA + (rt * 16 + ml) * 136 + ks * 32 + kh * 8);
        f32x4_t acc[4];
        #pragma unroll
        for (int q = 0; q < 4; ++q) acc[q] = (f32x4_t){0.f, 0.f, 0.f, 0.f};
        #pragma unroll
        for (int q = 0; q < 4; ++q) {
            int j = (jgrp * 4 + q) * 16 + ml;
            #pragma unroll
            for (int ks = 0; ks < 4; ++ks) {
                short8_t bfr = *(const short8_t*)(Wb + (size_t)j * D + ks * 32 + kh * 8);
                acc[q] = __builtin_amdgcn_mfma_f32_16x16x32_bf16(afr[ks], bfr, acc[q], 0, 0, 0);
            }
        }
        // C/D layout: col = lane&15 (j), row = (lane>>4)*4 + reg (n)
        #pragma unroll
        for (int q = 0; q < 4; ++q) {
            int j = (jgrp * 4 + q) * 16 + ml;
            float bj = bias[j];
            #pragma unroll
            for (int r = 0; r < 4; ++r) {
                int gn = nbase + rt * 16 + kh * 4 + r;
                if (gn < N) out[(size_t)gn * D + j] = acc[q][r] + bj;
            }
        }
    }
}

// ---- fallback Pass B: bucket -> packed global elist (fp32 path only) ----
__global__ __launch_bounds__(256) void prep_kernel(
    const int* __restrict__ gcur, const int* __restrict__ bucket,
    int* __restrict__ elist, int* __restrict__ cnt,
    int* __restrict__ start, int N, int NBUK) {
    __shared__ int lcnt[32], lpos[32], lstart[32];
    int t = threadIdx.x;
    int b = blockIdx.x;
    if (t < 32) { lcnt[t] = 0; lpos[t] = 0; }
    __syncthreads();
    int tot = min(gcur[b], BCAP);
    const int* bp = bucket + (size_t)b * BCAP;
    for (int i = t; i < tot; i += 256)
        atomicAdd(&lcnt[bp[i] >> 24], 1);
    __syncthreads();
    if (t == 0) {
        int run = 0;
        #pragma unroll
        for (int i = 0; i < 32; ++i) {
            lstart[i] = run;
            run += (lcnt[i] + 3) & ~3;     // 4-aligned segments
        }
    }
    __syncthreads();
    for (int i = t; i < tot; i += 256) {
        int v = bp[i];
        int rl = v >> 24;
        int p = atomicAdd(&lpos[rl], 1);
        int idx = lstart[rl] + p;
        if (idx < BCAP) elist[(size_t)b * BCAP + idx] = v & 0xFFFFFF;
    }
    if (t < 32) {
        int gr = (b << BSHIFT) + t;
        if (gr < N) { cnt[gr] = lcnt[t]; start[gr] = b * BCAP + lstart[t]; }
    }
}

// ---- fp32 fused variant (proven; used when ws can't hold xb).
// Reads only i < cnt entries. ----
__global__ __launch_bounds__(256, 6) void fused_kernel(
    const float* __restrict__ x, const int* __restrict__ elist,
    const int* __restrict__ cnt, const int* __restrict__ start,
    const float* __restrict__ W, const float* __restrict__ bias,
    float* __restrict__ out, int N) {
    __shared__ float sT[128 * 36];
    __shared__ float wc[16 * 132];
    int t = threadIdx.x;
    int lane = t & 63, wave = t >> 6;
    int half = lane >> 5, sl = lane & 31;
    int nbase = blockIdx.x * 32;

    #pragma unroll
    for (int pair = 0; pair < 4; ++pair) {
        int n = wave * 8 + pair * 2 + half;
        int gn = nbase + n;
        int nr  = (gn < N) ? cnt[gn]   : 0;
        int beg = (gn < N) ? start[gn] : 0;
        int nro  = __shfl(nr, lane ^ 32);
        int both = min(nr, nro);
        float ax = 0.f, ay = 0.f, az = 0.f, aw = 0.f;
        int i = 0;
        for (; i + 8 <= both; i += 8) {
            int4 cA = *(const int4*)(elist + beg + i);
            int4 cB = *(const int4*)(elist + beg + i + 4);
            float4 v0 = *(const float4*)(x + (size_t)cA.x * D + 4 * sl);
            float4 v1 = *(const float4*)(x + (size_t)cA.y * D + 4 * sl);
            float4 v2 = *(const float4*)(x + (size_t)cA.z * D + 4 * sl);
            float4 v3 = *(const float4*)(x + (size_t)cA.w * D + 4 * sl);
            float4 v4 = *(const float4*)(x + (size_t)cB.x * D + 4 * sl);
            float4 v5 = *(const float4*)(x + (size_t)cB.y * D + 4 * sl);
            float4 v6 = *(const float4*)(x + (size_t)cB.z * D + 4 * sl);
            float4 v7 = *(const float4*)(x + (size_t)cB.w * D + 4 * sl);
            ax += ((v0.x + v1.x) + (v2.x + v3.x)) + ((v4.x + v5.x) + (v6.x + v7.x));
            ay += ((v0.y + v1.y) + (v2.y + v3.y)) + ((v4.y + v5.y) + (v6.y + v7.y));
            az += ((v0.z + v1.z) + (v2.z + v3.z)) + ((v4.z + v5.z) + (v6.z + v7.z));
            aw += ((v0.w + v1.w) + (v2.w + v3.w)) + ((v4.w + v5.w) + (v6.w + v7.w));
        }
        for (; i < nr; ++i) {
            int c0 = elist[beg + i];
            float4 v = *(const float4*)(x + (size_t)c0 * D + 4 * sl);
            ax += v.x; ay += v.y; az += v.z; aw += v.w;
        }
        float inv = (nr > 0) ? 1.0f / (float)nr : 0.0f;
        int k0 = 4 * sl;
        sT[(k0 + 0) * 36 + n] = ax * inv;
        sT[(k0 + 1) * 36 + n] = ay * inv;
        sT[(k0 + 2) * 36 + n] = az * inv;
        sT[(k0 + 3) * 36 + n] = aw * inv;
    }

    int jg = t & 31, ng = t >> 5;
    int j0 = jg * 4, n0 = ng * 4;
    float acc[4][4] = {};
    for (int kc = 0; kc < 8; ++kc) {
        __syncthreads();
        #pragma unroll
        for (int i = 0; i < 8; ++i) {
            int idx = t + i * 256;
            int j = idx >> 4, kk = idx & 15;
            wc[kk * 132 + j] = W[j * D + kc * 16 + kk];
        }
        __syncthreads();
        #pragma unroll
        for (int kk = 0; kk < 16; ++kk) {
            int k = kc * 16 + kk;
            float4 s4 = *(const float4*)(sT + k * 36 + n0);
            float4 w4 = *(const float4*)(wc + kk * 132 + j0);
            acc[0][0] = fmaf(s4.x, w4.x, acc[0][0]); acc[0][1] = fmaf(s4.x, w4.y, acc[0][1]);
            acc[0][2] = fmaf(s4.x, w4.z, acc[0][2]); acc[0][3] = fmaf(s4.x, w4.w, acc[0][3]);
            acc[1][0] = fmaf(s4.y, w4.x, acc[1][0]); acc[1][1] = fmaf(s4.y, w4.y, acc[1][1]);
            acc[1][2] = fmaf(s4.y, w4.z, acc[1][2]); acc[1][3] = fmaf(s4.y, w4.w, acc[1][3]);
            acc[2][0] = fmaf(s4.z, w4.x, acc[2][0]); acc[2][1] = fmaf(s4.z, w4.y, acc[2][1]);
            acc[2][2] = fmaf(s4.z, w4.z, acc[2][2]); acc[2][3] = fmaf(s4.z, w4.w, acc[2][3]);
            acc[3][0] = fmaf(s4.w, w4.x, acc[3][0]); acc[3][1] = fmaf(s4.w, w4.y, acc[3][1]);
            acc[3][2] = fmaf(s4.w, w4.z, acc[3][2]); acc[3][3] = fmaf(s4.w, w4.w, acc[3][3]);
        }
    }
    float4 b4 = *(const float4*)(bias + j0);
    #pragma unroll
    for (int i = 0; i < 4; ++i) {
        int gn = nbase + n0 + i;
        if (gn >= N) continue;
        float4 o;
        o.x = acc[i][0] + b4.x;
        o.y = acc[i][1] + b4.y;
        o.z = acc[i][2] + b4.z;
        o.w = acc[i][3] + b4.w;
        *(float4*)(out + (size_t)gn * D + j0) = o;
    }
}

// ==== last-resort fallback: atomic scatter + divide + gemm (proven) ====
__global__ __launch_bounds__(256) void scatter_kernel(
    const float* __restrict__ x, const int* __restrict__ eidx,
    float* summed, float* __restrict__ counts, int E) {
    int t = blockIdx.x * 256 + threadIdx.x;
    int lane = threadIdx.x & 63;
    bool is64 = eidx_is64(eidx);
    int e = t >> 6;
    if (e >= E) return;
    int d = lane * 2;
    int r, c;
    if (is64) { r = eidx[2 * e]; c = eidx[2 * E + 2 * e]; }
    else      { r = eidx[e];     c = eidx[E + e]; }
    float2 v = *(const float2*)(x + (size_t)c * D + d);
    float* dst = summed + (size_t)r * D + d;
    atomicAdd(dst, v.x);
    atomicAdd(dst + 1, v.y);
    if (lane == 0) atomicAdd(counts + r, 1.0f);
}

__global__ __launch_bounds__(256) void divide_kernel(
    float* __restrict__ sums, const float* __restrict__ counts, int N) {
    int g = blockIdx.x * 256 + threadIdx.x;
    int r = g >> 6, lane = g & 63;
    if (r >= N) return;
    float inv = 1.0f / fmaxf(counts[r], 1.0f);
    float2* p = (float2*)(sums + (size_t)r * D + 2 * lane);
    float2 v = *p;
    v.x *= inv; v.y *= inv;
    *p = v;
}

__global__ __launch_bounds__(256) void gemm_kernel(
    float* inout, const float* __restrict__ W,
    const float* __restrict__ bias, int N) {
    __shared__ float sT[128 * 36];
    __shared__ float wc[32 * 132];
    int t = threadIdx.x;
    int nbase = blockIdx.x * 32;
    #pragma unroll
    for (int i = 0; i < 16; ++i) {
        int idx = t + i * 256;
        int n = idx >> 7, k = idx & 127;
        int gn = nbase + n;
        sT[k * 36 + n] = (gn < N) ? inout[(size_t)gn * D + k] : 0.0f;
    }
    int jg = t & 31, ng = t >> 5;
    int j0 = jg * 4, n0 = ng * 4;
    float acc[4][4] = {};
    for (int kc = 0; kc < 4; ++kc) {
        __syncthreads();
        #pragma unroll
        for (int i = 0; i < 16; ++i) {
            int idx = t + i * 256;
            int j = idx >> 5, kk = idx & 31;
            wc[kk * 132 + j] = W[j * D + kc * 32 + kk];
        }
        __syncthreads();
        #pragma unroll 8
        for (int kk = 0; kk < 32; ++kk) {
            int k = kc * 32 + kk;
            float4 s4 = *(const float4*)(sT + k * 36 + n0);
            float4 w4 = *(const float4*)(wc + kk * 132 + j0);
            acc[0][0] = fmaf(s4.x, w4.x, acc[0][0]); acc[0][1] = fmaf(s4.x, w4.y, acc[0][1]);
            acc[0][2] = fmaf(s4.x, w4.z, acc[0][2]); acc[0][3] = fmaf(s4.x, w4.w, acc[0][3]);
            acc[1][0] = fmaf(s4.y, w4.x, acc[1][0]); acc[1][1] = fmaf(s4.y, w4.y, acc[1][1]);
            acc[1][2] = fmaf(s4.y, w4.z, acc[1][2]); acc[1][3] = fmaf(s4.y, w4.w, acc[1][3]);
            acc[2][0] = fmaf(s4.z, w4.x, acc[2][0]); acc[2][1] = fmaf(s4.z, w4.y, acc[2][1]);
            acc[2][2] = fmaf(s4.z, w4.z, acc[2][2]); acc[2][3] = fmaf(s4.z, w4.w, acc[2][3]);
            acc[3][0] = fmaf(s4.w, w4.x, acc[3][0]); acc[3][1] = fmaf(s4.w, w4.y, acc[3][1]);
            acc[3][2] = fmaf(s4.w, w4.z, acc[3][2]); acc[3][3] = fmaf(s4.w, w4.w, acc[3][3]);
        }
    }
    float4 b4 = *(const float4*)(bias + j0);
    #pragma unroll
    for (int i = 0; i < 4; ++i) {
        int gn = nbase + n0 + i;
        if (gn >= N) continue;
        float4 o;
        o.x = acc[i][0] + b4.x;
        o.y = acc[i][1] + b4.y;
        o.z = acc[i][2] + b4.z;
        o.w = acc[i][3] + b4.w;
        *(float4*)(inout + (size_t)gn * D + j0) = o;
    }
}

extern "C" void kernel_launch(void* const* d_in, const int* in_sizes, int n_in,
                              void* d_out, int out_size, void* d_ws, size_t ws_size,
                              hipStream_t stream) {
    // setup_inputs order: x, edge_index, batch_size, num_nodes, W, b
    const float* x = (const float*)d_in[0];
    const int* eidx = (const int*)d_in[1];
    const float* W = (const float*)d_in[4];
    const float* b = (const float*)d_in[5];
    float* out = (float*)d_out;

    int N = in_sizes[0] / D;   // 50000
    int E = in_sizes[1] / 2;   // 800000
    int NBUK = (N + 31) >> BSHIFT;   // 1563
    int ab = (E + EPB_A - 1) / EPB_A;

    // ws layout, 256B-aligned segments (cnt/start/elist used by fallback only).
    size_t o0 = 0;
    size_t o_gc = o0;  o0 += ((size_t)NBUK * 4 + 255) & ~255ULL;
    size_t o_cn = o0;  o0 += ((size_t)N * 4 + 255) & ~255ULL;
    size_t o_st = o0;  o0 += ((size_t)N * 4 + 255) & ~255ULL;
    size_t o_bk = o0;  o0 += (size_t)NBUK * BCAP * 4;
    size_t o_el = o0;  o0 += (size_t)NBUK * BCAP * 4;
    size_t base_need = o0;
    size_t o_xb = o0;  o0 += (((size_t)(N + 1) * D * 2) + 255) & ~255ULL;  // bf16 x + dummy
    size_t o_wb = o0;  size_t bf_need = o0 + (size_t)D * D * 2;            // bf16 W

    bool cap_ok = (N <= 65536) && ((size_t)NBUK * BCAP >= (size_t)E);

    int cvb = (N * D / 8 + 255) / 256;
    int wvb = (D * D / 8 + 255) / 256;   // 8 blocks for W conversion

    if (cap_ok && ws_size >= bf_need) {
        char* ws = (char*)d_ws;
        int*      gcur  = (int*)(ws + o_gc);
        int*      bkt   = (int*)(ws + o_bk);
        ushort_t* xb    = (ushort_t*)(ws + o_xb);
        ushort_t* wb    = (ushort_t*)(ws + o_wb);

        hipMemsetAsync(gcur, 0, (size_t)NBUK * 4, stream);  // 6 KB only
        pre_kernel<<<ab + cvb + wvb, 256, 0, stream>>>(
            eidx, gcur, bkt, E, NBUK, ab,
            x, (uint_t*)xb, N * D / 8, cvb, W, (uint_t*)wb, N);
        fused_bf_kernel<<<NBUK, 256, 0, stream>>>(xb, gcur, bkt, wb, b, out, N);
    } else if (cap_ok && ws_size >= base_need) {
        char* ws = (char*)d_ws;
        int* gcur  = (int*)(ws + o_gc);
        int* cnt   = (int*)(ws + o_cn);
        int* start = (int*)(ws + o_st);
        int* bkt   = (int*)(ws + o_bk);
        int* elist = (int*)(ws + o_el);
        int fb = (N + 31) / 32;

        hipMemsetAsync(gcur, 0, (size_t)NBUK * 4, stream);
        pre_kernel<<<ab, 256, 0, stream>>>(
            eidx, gcur, bkt, E, NBUK, ab,
            nullptr, nullptr, 0, 0, nullptr, nullptr, N);
        prep_kernel<<<NBUK, 256, 0, stream>>>(gcur, bkt, elist, cnt, start, N, NBUK);
        fused_kernel<<<fb, 256, 0, stream>>>(x, elist, cnt, start, W, b, out, N);
    } else {
        float* counts = (float*)d_ws;
        int fb = (N + 31) / 32;
        hipMemsetAsync(d_out, 0, (size_t)N * D * sizeof(float), stream);
        hipMemsetAsync(d_ws, 0, (size_t)N * sizeof(float), stream);
        int sb = (E * 64 + 255) / 256;
        scatter_kernel<<<sb, 256, 0, stream>>>(x, eidx, out, counts, E);
        int db = (N * 64 + 255) / 256;
        divide_kernel<<<db, 256, 0, stream>>>(out, counts, N);
        gemm_kernel<<<fb, 256, 0, stream>>>(out, W, b, N);
    }
}

// Round 14
// 155.745 us; speedup vs baseline: 1.1340x; 1.0337x over previous
//
#include <hip/hip_runtime.h>

#define D 128
#define BSHIFT 5                 // 32 rows per bucket
#define BCAP 1024                // entries/bucket; mean 512, +16 sigma
#define EPB_A 2048               // edges per pass-A block (8 contiguous/thread)
                                 // R12: 1024 doubled per-block fixed cost (+19us)

typedef unsigned short ushort_t;
typedef unsigned int uint_t;
typedef __attribute__((ext_vector_type(8))) short short8_t;   // 8 bf16 = 4 VGPR
typedef __attribute__((ext_vector_type(4))) float f32x4_t;    // mfma C/D
typedef __attribute__((ext_vector_type(4))) uint_t uint4_t;   // asm ds_read dst
typedef const __attribute__((address_space(1))) void* gas_cptr;
typedef __attribute__((address_space(3))) void* las_ptr;
typedef const __attribute__((address_space(3))) ushort_t* las_cushort;

// ---- edge-index dtype probe (int64 vs int32), wave-uniform, ~free ----
__device__ __forceinline__ bool eidx_is64(const int* eidx) {
    int lane = threadIdx.x & 63;
    int probe = eidx[2 * lane + 1];              // L2-hit after first wave
    return __ballot(probe != 0) == 0ULL;         // int64 high halves all zero
}

__device__ __forceinline__ uint_t f2bf(float f) {
    union { float f; uint_t i; } v; v.f = f;
    return (v.i + 0x7fffu + ((v.i >> 16) & 1u)) >> 16;   // RNE
}
__device__ __forceinline__ float bf_lo(uint_t w) {
    union { uint_t i; float f; } v; v.i = w << 16; return v.f;
}
__device__ __forceinline__ float bf_hi(uint_t w) {
    union { uint_t i; float f; } v; v.i = w & 0xffff0000u; return v.f;
}

// ==== Kernel 1: bucketA + fp32->bf16 conv of x AND W (all independent) ====
// Final config: EPB_A 2048 (391 blocks, 8 contiguous edges/thread, int4).
// Ledger: fixed harness overhead ~66us; fused gather random-line-HBM-bound
// at ~52.5us; pre ~39us -> structural floor ~157us total.
__global__ __launch_bounds__(256) void pre_kernel(
    const int* __restrict__ eidx, int* __restrict__ gcur,
    int* __restrict__ bucket, int E, int NBUK, int ab,
    const float* __restrict__ x, uint_t* __restrict__ xb, int total8, int cvb,
    const float* __restrict__ Wsrc, uint_t* __restrict__ wb, int N) {
    int t = threadIdx.x;

    if ((int)blockIdx.x >= ab) {                 // ---- conv roles ----
        if (xb == nullptr) return;
        int cb = blockIdx.x - ab;
        if (cb < cvb) {                          // x conversion
            int i = cb * 256 + t;
            if (i < total8) {                    // one thread = 8 elems
                const float4* p = (const float4*)(x + (size_t)i * 8);
                float4 a = p[0], b = p[1];
                uint4 o;
                o.x = f2bf(a.x) | (f2bf(a.y) << 16);
                o.y = f2bf(a.z) | (f2bf(a.w) << 16);
                o.z = f2bf(b.x) | (f2bf(b.y) << 16);
                o.w = f2bf(b.z) | (f2bf(b.w) << 16);
                *(uint4*)(xb + (size_t)i * 4) = o;
            }
            if (cb == 0 && t < 16) {
                // dummy zero row at index N: xb is uint_t* here, row N starts
                // at uint offset N*(D/2) (byte N*256).
                uint4 z; z.x = 0u; z.y = 0u; z.z = 0u; z.w = 0u;
                ((uint4*)(xb + (size_t)N * (D / 2)))[t] = z;
            }
        } else {                                 // W conversion (D*D/8 = 2048 items)
            int i = (cb - cvb) * 256 + t;
            if (i < D * D / 8) {
                const float4* p = (const float4*)(Wsrc + (size_t)i * 8);
                float4 a = p[0], b = p[1];
                uint4 o;
                o.x = f2bf(a.x) | (f2bf(a.y) << 16);
                o.y = f2bf(a.z) | (f2bf(a.w) << 16);
                o.z = f2bf(b.x) | (f2bf(b.y) << 16);
                o.w = f2bf(b.z) | (f2bf(b.w) << 16);
                *(uint4*)(wb + (size_t)i * 4) = o;
            }
        }
        return;
    }

    // ---- bucketA role: coarse-bucket edges, contiguous vector reads ----
    __shared__ int lhist[2048];   // supports N <= 65536 at 32 rows/bucket
    __shared__ int lbase[2048];
    bool is64 = eidx_is64(eidx);
    for (int i = t; i < NBUK; i += 256) lhist[i] = 0;
    __syncthreads();

    int e0 = blockIdx.x * EPB_A;
    int e1 = min(e0 + EPB_A, E);
    int base = e0 + 8 * t;                    // 8 contiguous edges per thread
    int rr[8], cc[8];
    #pragma unroll
    for (int k = 0; k < 8; ++k) rr[k] = -1;
    if (is64) {
        if (base + 8 <= e1 && (E & 1) == 0) { // int4-aligned fast path
            const int4* rp = (const int4*)(eidx + 2 * (size_t)base);
            const int4* cp = (const int4*)(eidx + 2 * (size_t)E + 2 * (size_t)base);
            #pragma unroll
            for (int g = 0; g < 4; ++g) {
                int4 r = rp[g], c = cp[g];
                rr[2 * g]     = r.x; cc[2 * g]     = c.x;
                rr[2 * g + 1] = r.z; cc[2 * g + 1] = c.z;
            }
        } else {
            #pragma unroll
            for (int k = 0; k < 8; ++k) {
                int e = base + k;
                if (e < e1) { rr[k] = eidx[2 * e]; cc[k] = eidx[2 * E + 2 * e]; }
            }
        }
    } else {
        if (base + 8 <= e1 && (E & 3) == 0) { // int4-aligned fast path
            const int4* rp = (const int4*)(eidx + base);
            const int4* cp = (const int4*)(eidx + (size_t)E + base);
            int4 r0 = rp[0], r1 = rp[1], c0 = cp[0], c1 = cp[1];
            rr[0] = r0.x; rr[1] = r0.y; rr[2] = r0.z; rr[3] = r0.w;
            rr[4] = r1.x; rr[5] = r1.y; rr[6] = r1.z; rr[7] = r1.w;
            cc[0] = c0.x; cc[1] = c0.y; cc[2] = c0.z; cc[3] = c0.w;
            cc[4] = c1.x; cc[5] = c1.y; cc[6] = c1.z; cc[7] = c1.w;
        } else {
            #pragma unroll
            for (int k = 0; k < 8; ++k) {
                int e = base + k;
                if (e < e1) { rr[k] = eidx[e]; cc[k] = eidx[E + e]; }
            }
        }
    }
    #pragma unroll
    for (int k = 0; k < 8; ++k)
        if (rr[k] >= 0) atomicAdd(&lhist[rr[k] >> BSHIFT], 1);
    __syncthreads();
    for (int i = t; i < NBUK; i += 256) {
        int h = lhist[i];
        lbase[i] = (h > 0) ? atomicAdd(&gcur[i], h) : 0;
        lhist[i] = 0;
    }
    __syncthreads();
    #pragma unroll
    for (int k = 0; k < 8; ++k) {             // scatter from regs (no re-read)
        if (rr[k] >= 0) {
            int b = rr[k] >> BSHIFT;
            int p = atomicAdd(&lhist[b], 1);   // LDS: cheap
            int idx = lbase[b] + p;
            if (idx < BCAP) bucket[b * BCAP + idx] = ((rr[k] & 31) << 24) | cc[k];
        }
    }
}

// ==== Kernel 2: FUSED bucketB (LDS) + 2-deep global_load_lds + MFMA ====
// Final config = union of verified-best pieces: R7's 2-deep counted-vmcnt
// asm-consume pipeline (52.4us) + R10's step-1 single-pass reg-read.
// R13 refuted quartile cache-blocking (FETCH unchanged, +4us sort cost).
#define ISSUE(c, bufsel)                                                      \
    {                                                                         \
        ushort_t* db_ = wstage + (bufsel) * 2048;                             \
        __builtin_amdgcn_global_load_lds(                                     \
            (gas_cptr)(xb + (size_t)(c).x * D + 8 * sl),                      \
            (las_ptr)(db_), 16, 0, 0);                                        \
        __builtin_amdgcn_global_load_lds(                                     \
            (gas_cptr)(xb + (size_t)(c).y * D + 8 * sl),                      \
            (las_ptr)(db_ + 512), 16, 0, 0);                                  \
        __builtin_amdgcn_global_load_lds(                                     \
            (gas_cptr)(xb + (size_t)(c).z * D + 8 * sl),                      \
            (las_ptr)(db_ + 1024), 16, 0, 0);                                 \
        __builtin_amdgcn_global_load_lds(                                     \
            (gas_cptr)(xb + (size_t)(c).w * D + 8 * sl),                      \
            (las_ptr)(db_ + 1536), 16, 0, 0);                                 \
    }

#define ACCV(v)                                                               \
    a0 += bf_lo((v)[0]); a1 += bf_hi((v)[0]);                                 \
    a2 += bf_lo((v)[1]); a3 += bf_hi((v)[1]);                                 \
    a4 += bf_lo((v)[2]); a5 += bf_hi((v)[2]);                                 \
    a6 += bf_lo((v)[3]); a7 += bf_hi((v)[3]);

// consume one 4-edge batch via inline-asm ds_read (invisible to the compiler
// vmcnt legalizer -- R6 lesson: visible LDS reads get s_waitcnt vmcnt(0))
#define CONSUME                                                               \
    {                                                                         \
        uint4_t v0, v1, v2, v3;                                               \
        asm volatile("ds_read_b128 %0, %1"             : "=v"(v0) : "v"(sbp));\
        asm volatile("ds_read_b128 %0, %1 offset:1024" : "=v"(v1) : "v"(sbp));\
        asm volatile("ds_read_b128 %0, %1 offset:2048" : "=v"(v2) : "v"(sbp));\
        asm volatile("ds_read_b128 %0, %1 offset:3072" : "=v"(v3) : "v"(sbp));\
        asm volatile("s_waitcnt lgkmcnt(0)" ::: "memory");                    \
        __builtin_amdgcn_sched_barrier(0);                                    \
        ACCV(v0) ACCV(v1) ACCV(v2) ACCV(v3)                                   \
    }

__global__ __launch_bounds__(256, 3) void fused_bf_kernel(
    const ushort_t* __restrict__ xb, const int* __restrict__ gcur,
    const int* __restrict__ bucket, const ushort_t* __restrict__ Wb,
    const float* __restrict__ bias, float* __restrict__ out, int N) {
    __shared__ alignas(16) int sE[1152];          // 4.5 KiB packed 4-padded list
    __shared__ int lcnt[32], lpos[32], lstart[32];
    __shared__ alignas(16) ushort_t sA[32 * 136]; // 8.5 KiB [n][k] bf16 +pad
    __shared__ alignas(16) ushort_t stage[16384]; // 32 KiB 4 waves x 2 x 4 KB
    int t = threadIdx.x;
    int b = blockIdx.x;

    // ---- step 1: bucketB in LDS (bucket entries read ONCE into regs) ----
    if (t < 32) { lcnt[t] = 0; lpos[t] = 0; }
    __syncthreads();
    int tot = min(gcur[b], BCAP);
    const int* bp = bucket + (size_t)b * BCAP;
    int4 ev = make_int4(-1, -1, -1, -1);          // entries >= 0; -1 = invalid
    if (4 * t + 3 < tot) {
        ev = *(const int4*)(bp + 4 * t);
    } else {
        if (4 * t + 0 < tot) ev.x = bp[4 * t + 0];
        if (4 * t + 1 < tot) ev.y = bp[4 * t + 1];
        if (4 * t + 2 < tot) ev.z = bp[4 * t + 2];
        if (4 * t + 3 < tot) ev.w = bp[4 * t + 3];
    }
    if (ev.x >= 0) atomicAdd(&lcnt[ev.x >> 24], 1);
    if (ev.y >= 0) atomicAdd(&lcnt[ev.y >> 24], 1);
    if (ev.z >= 0) atomicAdd(&lcnt[ev.z >> 24], 1);
    if (ev.w >= 0) atomicAdd(&lcnt[ev.w >> 24], 1);
    __syncthreads();
    if (t == 0) {
        int run = 0;
        #pragma unroll
        for (int i = 0; i < 32; ++i) {
            lstart[i] = run;
            run += (lcnt[i] + 3) & ~3;     // 4-aligned, 4-padded segments
        }                                  // run <= 1024 + 32*3 = 1120 < 1152
    }
    __syncthreads();
    {
        int v[4] = { ev.x, ev.y, ev.z, ev.w };
        #pragma unroll
        for (int q = 0; q < 4; ++q) {
            if (v[q] >= 0) {
                int rl = v[q] >> 24;
                int p = atomicAdd(&lpos[rl], 1);
                int idx = lstart[rl] + p;
                if (idx < 1152) sE[idx] = v[q] & 0xFFFFFF;
            }
        }
    }
    if (t < 32) {                          // pad with dummy (zero) row index N
        int c0 = lcnt[t];
        int pe = (c0 + 3) & ~3;
        for (int p = c0; p < pe; ++p) {
            int idx = lstart[t] + p;
            if (idx < 1152) sE[idx] = N;
        }
    }
    __syncthreads();

    // ---- step 2: gather means -> bf16 LDS A-tile (2-deep staging) ----
    int lane = t & 63, wave = t >> 6;
    int qi = t >> 4, sl = t & 15;          // quarter [0,16), sublane [0,16)
    int nbase = b << BSHIFT;               // 32 rows per block
    ushort_t* wstage = stage + (wave << 12);   // 8 KB (4096 ushorts) per wave

    #pragma unroll
    for (int quad = 0; quad < 2; ++quad) {
        int n = 2 * qi + quad;             // row within bucket [0,32)
        int nr = lcnt[n];
        int st = lstart[n];                // 4-aligned
        int trips = ((nr + 3) & ~3) >> 2;  // 4-edge batches
        int wmax = trips;                  // wave-uniform trip count
        wmax = max(wmax, __shfl_xor(wmax, 16));
        wmax = max(wmax, __shfl_xor(wmax, 32));
        float a0 = 0.f, a1 = 0.f, a2 = 0.f, a3 = 0.f;
        float a4 = 0.f, a5 = 0.f, a6 = 0.f, a7 = 0.f;
        if (wmax > 0) {
            int4 cc0 = (0 < trips) ? *(const int4*)(sE + st)
                                   : make_int4(N, N, N, N);
            ISSUE(cc0, 0)
            __builtin_amdgcn_sched_barrier(0);
            for (int bt = 0; bt < wmax; ++bt) {
                int buf = bt & 1;
                if (bt + 1 < wmax) {       // wave-uniform branch
                    int4 cn = (bt + 1 < trips)
                        ? *(const int4*)(sE + st + 4 * (bt + 1))
                        : make_int4(N, N, N, N);
                    ISSUE(cn, buf ^ 1)
                    __builtin_amdgcn_sched_barrier(0);
                    asm volatile("s_waitcnt vmcnt(4)" ::: "memory");
                } else {
                    asm volatile("s_waitcnt vmcnt(0)" ::: "memory");
                }
                __builtin_amdgcn_sched_barrier(0);
                las_cushort sbp = (las_cushort)(wstage + buf * 2048 + lane * 8);
                CONSUME
            }
        }
        float inv = (nr > 0) ? 1.0f / (float)nr : 0.0f;
        uint4 pk;
        pk.x = f2bf(a0 * inv) | (f2bf(a1 * inv) << 16);
        pk.y = f2bf(a2 * inv) | (f2bf(a3 * inv) << 16);
        pk.z = f2bf(a4 * inv) | (f2bf(a5 * inv) << 16);
        pk.w = f2bf(a6 * inv) | (f2bf(a7 * inv) << 16);
        *(uint4*)(sA + n * 136 + 8 * sl) = pk;
    }
    __syncthreads();

    // ---- step 3: out[n][j] = mean[n][:] . W[j][:] + b[j]  via MFMA ----
    // 4 waves: rt = wave&1 (2 row-tiles of 16), jgrp = wave>>1 (4 j-tiles).
    // A-frag: lane holds A[l&15][(l>>4)*8 + e];  B = W^T so lane reads
    // W[j = jt*16 + (l&15)][k .. k+7] -- contiguous global bf16.
    {
        int rt = wave & 1, jgrp = wave >> 1;
        int ml = lane & 15, kh = lane >> 4;
        short8_t afr[4];
        #pragma unroll
        for (int ks = 0; ks < 4; ++ks)
            afr[ks] = *(const short8_t*)(sA + (rt * 16 + ml) * 136 + ks * 32 + kh * 8);
        f32x4_t acc[4];
        #pragma unroll
        for (int q = 0; q < 4; ++q) acc[q] = (f32x4_t){0.f, 0.f, 0.f, 0.f};
        #pragma unroll
        for (int q = 0; q < 4; ++q) {
            int j = (jgrp * 4 + q) * 16 + ml;
            #pragma unroll
            for (int ks = 0; ks < 4; ++ks) {
                short8_t bfr = *(const short8_t*)(Wb + (size_t)j * D + ks * 32 + kh * 8);
                acc[q] = __builtin_amdgcn_mfma_f32_16x16x32_bf16(afr[ks], bfr, acc[q], 0, 0, 0);
            }
        }
        // C/D layout: col = lane&15 (j), row = (lane>>4)*4 + reg (n)
        #pragma unroll
        for (int q = 0; q < 4; ++q) {
            int j = (jgrp * 4 + q) * 16 + ml;
            float bj = bias[j];
            #pragma unroll
            for (int r = 0; r < 4; ++r) {
                int gn = nbase + rt * 16 + kh * 4 + r;
                if (gn < N) out[(size_t)gn * D + j] = acc[q][r] + bj;
            }
        }
    }
}

// ---- fallback Pass B: bucket -> packed global elist (fp32 path only) ----
__global__ __launch_bounds__(256) void prep_kernel(
    const int* __restrict__ gcur, const int* __restrict__ bucket,
    int* __restrict__ elist, int* __restrict__ cnt,
    int* __restrict__ start, int N, int NBUK) {
    __shared__ int lcnt[32], lpos[32], lstart[32];
    int t = threadIdx.x;
    int b = blockIdx.x;
    if (t < 32) { lcnt[t] = 0; lpos[t] = 0; }
    __syncthreads();
    int tot = min(gcur[b], BCAP);
    const int* bp = bucket + (size_t)b * BCAP;
    for (int i = t; i < tot; i += 256)
        atomicAdd(&lcnt[bp[i] >> 24], 1);
    __syncthreads();
    if (t == 0) {
        int run = 0;
        #pragma unroll
        for (int i = 0; i < 32; ++i) {
            lstart[i] = run;
            run += (lcnt[i] + 3) & ~3;     // 4-aligned segments
        }
    }
    __syncthreads();
    for (int i = t; i < tot; i += 256) {
        int v = bp[i];
        int rl = v >> 24;
        int p = atomicAdd(&lpos[rl], 1);
        int idx = lstart[rl] + p;
        if (idx < BCAP) elist[(size_t)b * BCAP + idx] = v & 0xFFFFFF;
    }
    if (t < 32) {
        int gr = (b << BSHIFT) + t;
        if (gr < N) { cnt[gr] = lcnt[t]; start[gr] = b * BCAP + lstart[t]; }
    }
}

// ---- fp32 fused variant (proven; used when ws can't hold xb).
// Reads only i < cnt entries. ----
__global__ __launch_bounds__(256, 6) void fused_kernel(
    const float* __restrict__ x, const int* __restrict__ elist,
    const int* __restrict__ cnt, const int* __restrict__ start,
    const float* __restrict__ W, const float* __restrict__ bias,
    float* __restrict__ out, int N) {
    __shared__ float sT[128 * 36];
    __shared__ float wc[16 * 132];
    int t = threadIdx.x;
    int lane = t & 63, wave = t >> 6;
    int half = lane >> 5, sl = lane & 31;
    int nbase = blockIdx.x * 32;

    #pragma unroll
    for (int pair = 0; pair < 4; ++pair) {
        int n = wave * 8 + pair * 2 + half;
        int gn = nbase + n;
        int nr  = (gn < N) ? cnt[gn]   : 0;
        int beg = (gn < N) ? start[gn] : 0;
        int nro  = __shfl(nr, lane ^ 32);
        int both = min(nr, nro);
        float ax = 0.f, ay = 0.f, az = 0.f, aw = 0.f;
        int i = 0;
        for (; i + 8 <= both; i += 8) {
            int4 cA = *(const int4*)(elist + beg + i);
            int4 cB = *(const int4*)(elist + beg + i + 4);
            float4 v0 = *(const float4*)(x + (size_t)cA.x * D + 4 * sl);
            float4 v1 = *(const float4*)(x + (size_t)cA.y * D + 4 * sl);
            float4 v2 = *(const float4*)(x + (size_t)cA.z * D + 4 * sl);
            float4 v3 = *(const float4*)(x + (size_t)cA.w * D + 4 * sl);
            float4 v4 = *(const float4*)(x + (size_t)cB.x * D + 4 * sl);
            float4 v5 = *(const float4*)(x + (size_t)cB.y * D + 4 * sl);
            float4 v6 = *(const float4*)(x + (size_t)cB.z * D + 4 * sl);
            float4 v7 = *(const float4*)(x + (size_t)cB.w * D + 4 * sl);
            ax += ((v0.x + v1.x) + (v2.x + v3.x)) + ((v4.x + v5.x) + (v6.x + v7.x));
            ay += ((v0.y + v1.y) + (v2.y + v3.y)) + ((v4.y + v5.y) + (v6.y + v7.y));
            az += ((v0.z + v1.z) + (v2.z + v3.z)) + ((v4.z + v5.z) + (v6.z + v7.z));
            aw += ((v0.w + v1.w) + (v2.w + v3.w)) + ((v4.w + v5.w) + (v6.w + v7.w));
        }
        for (; i < nr; ++i) {
            int c0 = elist[beg + i];
            float4 v = *(const float4*)(x + (size_t)c0 * D + 4 * sl);
            ax += v.x; ay += v.y; az += v.z; aw += v.w;
        }
        float inv = (nr > 0) ? 1.0f / (float)nr : 0.0f;
        int k0 = 4 * sl;
        sT[(k0 + 0) * 36 + n] = ax * inv;
        sT[(k0 + 1) * 36 + n] = ay * inv;
        sT[(k0 + 2) * 36 + n] = az * inv;
        sT[(k0 + 3) * 36 + n] = aw * inv;
    }

    int jg = t & 31, ng = t >> 5;
    int j0 = jg * 4, n0 = ng * 4;
    float acc[4][4] = {};
    for (int kc = 0; kc < 8; ++kc) {
        __syncthreads();
        #pragma unroll
        for (int i = 0; i < 8; ++i) {
            int idx = t + i * 256;
            int j = idx >> 4, kk = idx & 15;
            wc[kk * 132 + j] = W[j * D + kc * 16 + kk];
        }
        __syncthreads();
        #pragma unroll
        for (int kk = 0; kk < 16; ++kk) {
            int k = kc * 16 + kk;
            float4 s4 = *(const float4*)(sT + k * 36 + n0);
            float4 w4 = *(const float4*)(wc + kk * 132 + j0);
            acc[0][0] = fmaf(s4.x, w4.x, acc[0][0]); acc[0][1] = fmaf(s4.x, w4.y, acc[0][1]);
            acc[0][2] = fmaf(s4.x, w4.z, acc[0][2]); acc[0][3] = fmaf(s4.x, w4.w, acc[0][3]);
            acc[1][0] = fmaf(s4.y, w4.x, acc[1][0]); acc[1][1] = fmaf(s4.y, w4.y, acc[1][1]);
            acc[1][2] = fmaf(s4.y, w4.z, acc[1][2]); acc[1][3] = fmaf(s4.y, w4.w, acc[1][3]);
            acc[2][0] = fmaf(s4.z, w4.x, acc[2][0]); acc[2][1] = fmaf(s4.z, w4.y, acc[2][1]);
            acc[2][2] = fmaf(s4.z, w4.z, acc[2][2]); acc[2][3] = fmaf(s4.z, w4.w, acc[2][3]);
            acc[3][0] = fmaf(s4.w, w4.x, acc[3][0]); acc[3][1] = fmaf(s4.w, w4.y, acc[3][1]);
            acc[3][2] = fmaf(s4.w, w4.z, acc[3][2]); acc[3][3] = fmaf(s4.w, w4.w, acc[3][3]);
        }
    }
    float4 b4 = *(const float4*)(bias + j0);
    #pragma unroll
    for (int i = 0; i < 4; ++i) {
        int gn = nbase + n0 + i;
        if (gn >= N) continue;
        float4 o;
        o.x = acc[i][0] + b4.x;
        o.y = acc[i][1] + b4.y;
        o.z = acc[i][2] + b4.z;
        o.w = acc[i][3] + b4.w;
        *(float4*)(out + (size_t)gn * D + j0) = o;
    }
}

// ==== last-resort fallback: atomic scatter + divide + gemm (proven) ====
__global__ __launch_bounds__(256) void scatter_kernel(
    const float* __restrict__ x, const int* __restrict__ eidx,
    float* summed, float* __restrict__ counts, int E) {
    int t = blockIdx.x * 256 + threadIdx.x;
    int lane = threadIdx.x & 63;
    bool is64 = eidx_is64(eidx);
    int e = t >> 6;
    if (e >= E) return;
    int d = lane * 2;
    int r, c;
    if (is64) { r = eidx[2 * e]; c = eidx[2 * E + 2 * e]; }
    else      { r = eidx[e];     c = eidx[E + e]; }
    float2 v = *(const float2*)(x + (size_t)c * D + d);
    float* dst = summed + (size_t)r * D + d;
    atomicAdd(dst, v.x);
    atomicAdd(dst + 1, v.y);
    if (lane == 0) atomicAdd(counts + r, 1.0f);
}

__global__ __launch_bounds__(256) void divide_kernel(
    float* __restrict__ sums, const float* __restrict__ counts, int N) {
    int g = blockIdx.x * 256 + threadIdx.x;
    int r = g >> 6, lane = g & 63;
    if (r >= N) return;
    float inv = 1.0f / fmaxf(counts[r], 1.0f);
    float2* p = (float2*)(sums + (size_t)r * D + 2 * lane);
    float2 v = *p;
    v.x *= inv; v.y *= inv;
    *p = v;
}

__global__ __launch_bounds__(256) void gemm_kernel(
    float* inout, const float* __restrict__ W,
    const float* __restrict__ bias, int N) {
    __shared__ float sT[128 * 36];
    __shared__ float wc[32 * 132];
    int t = threadIdx.x;
    int nbase = blockIdx.x * 32;
    #pragma unroll
    for (int i = 0; i < 16; ++i) {
        int idx = t + i * 256;
        int n = idx >> 7, k = idx & 127;
        int gn = nbase + n;
        sT[k * 36 + n] = (gn < N) ? inout[(size_t)gn * D + k] : 0.0f;
    }
    int jg = t & 31, ng = t >> 5;
    int j0 = jg * 4, n0 = ng * 4;
    float acc[4][4] = {};
    for (int kc = 0; kc < 4; ++kc) {
        __syncthreads();
        #pragma unroll
        for (int i = 0; i < 16; ++i) {
            int idx = t + i * 256;
            int j = idx >> 5, kk = idx & 31;
            wc[kk * 132 + j] = W[j * D + kc * 32 + kk];
        }
        __syncthreads();
        #pragma unroll 8
        for (int kk = 0; kk < 32; ++kk) {
            int k = kc * 32 + kk;
            float4 s4 = *(const float4*)(sT + k * 36 + n0);
            float4 w4 = *(const float4*)(wc + kk * 132 + j0);
            acc[0][0] = fmaf(s4.x, w4.x, acc[0][0]); acc[0][1] = fmaf(s4.x, w4.y, acc[0][1]);
            acc[0][2] = fmaf(s4.x, w4.z, acc[0][2]); acc[0][3] = fmaf(s4.x, w4.w, acc[0][3]);
            acc[1][0] = fmaf(s4.y, w4.x, acc[1][0]); acc[1][1] = fmaf(s4.y, w4.y, acc[1][1]);
            acc[1][2] = fmaf(s4.y, w4.z, acc[1][2]); acc[1][3] = fmaf(s4.y, w4.w, acc[1][3]);
            acc[2][0] = fmaf(s4.z, w4.x, acc[2][0]); acc[2][1] = fmaf(s4.z, w4.y, acc[2][1]);
            acc[2][2] = fmaf(s4.z, w4.z, acc[2][2]); acc[2][3] = fmaf(s4.z, w4.w, acc[2][3]);
            acc[3][0] = fmaf(s4.w, w4.x, acc[3][0]); acc[3][1] = fmaf(s4.w, w4.y, acc[3][1]);
            acc[3][2] = fmaf(s4.w, w4.z, acc[3][2]); acc[3][3] = fmaf(s4.w, w4.w, acc[3][3]);
        }
    }
    float4 b4 = *(const float4*)(bias + j0);
    #pragma unroll
    for (int i = 0; i < 4; ++i) {
        int gn = nbase + n0 + i;
        if (gn >= N) continue;
        float4 o;
        o.x = acc[i][0] + b4.x;
        o.y = acc[i][1] + b4.y;
        o.z = acc[i][2] + b4.z;
        o.w = acc[i][3] + b4.w;
        *(float4*)(inout + (size_t)gn * D + j0) = o;
    }
}

extern "C" void kernel_launch(void* const* d_in, const int* in_sizes, int n_in,
                              void* d_out, int out_size, void* d_ws, size_t ws_size,
                              hipStream_t stream) {
    // setup_inputs order: x, edge_index, batch_size, num_nodes, W, b
    const float* x = (const float*)d_in[0];
    const int* eidx = (const int*)d_in[1];
    const float* W = (const float*)d_in[4];
    const float* b = (const float*)d_in[5];
    float* out = (float*)d_out;

    int N = in_sizes[0] / D;   // 50000
    int E = in_sizes[1] / 2;   // 800000
    int NBUK = (N + 31) >> BSHIFT;   // 1563
    int ab = (E + EPB_A - 1) / EPB_A;

    // ws layout, 256B-aligned segments (cnt/start/elist used by fallback only).
    size_t o0 = 0;
    size_t o_gc = o0;  o0 += ((size_t)NBUK * 4 + 255) & ~255ULL;
    size_t o_cn = o0;  o0 += ((size_t)N * 4 + 255) & ~255ULL;
    size_t o_st = o0;  o0 += ((size_t)N * 4 + 255) & ~255ULL;
    size_t o_bk = o0;  o0 += (size_t)NBUK * BCAP * 4;
    size_t o_el = o0;  o0 += (size_t)NBUK * BCAP * 4;
    size_t base_need = o0;
    size_t o_xb = o0;  o0 += (((size_t)(N + 1) * D * 2) + 255) & ~255ULL;  // bf16 x + dummy
    size_t o_wb = o0;  size_t bf_need = o0 + (size_t)D * D * 2;            // bf16 W

    bool cap_ok = (N <= 65536) && ((size_t)NBUK * BCAP >= (size_t)E);

    int cvb = (N * D / 8 + 255) / 256;
    int wvb = (D * D / 8 + 255) / 256;   // 8 blocks for W conversion

    if (cap_ok && ws_size >= bf_need) {
        char* ws = (char*)d_ws;
        int*      gcur  = (int*)(ws + o_gc);
        int*      bkt   = (int*)(ws + o_bk);
        ushort_t* xb    = (ushort_t*)(ws + o_xb);
        ushort_t* wb    = (ushort_t*)(ws + o_wb);

        hipMemsetAsync(gcur, 0, (size_t)NBUK * 4, stream);  // 6 KB only
        pre_kernel<<<ab + cvb + wvb, 256, 0, stream>>>(
            eidx, gcur, bkt, E, NBUK, ab,
            x, (uint_t*)xb, N * D / 8, cvb, W, (uint_t*)wb, N);
        fused_bf_kernel<<<NBUK, 256, 0, stream>>>(xb, gcur, bkt, wb, b, out, N);
    } else if (cap_ok && ws_size >= base_need) {
        char* ws = (char*)d_ws;
        int* gcur  = (int*)(ws + o_gc);
        int* cnt   = (int*)(ws + o_cn);
        int* start = (int*)(ws + o_st);
        int* bkt   = (int*)(ws + o_bk);
        int* elist = (int*)(ws + o_el);
        int fb = (N + 31) / 32;

        hipMemsetAsync(gcur, 0, (size_t)NBUK * 4, stream);
        pre_kernel<<<ab, 256, 0, stream>>>(
            eidx, gcur, bkt, E, NBUK, ab,
            nullptr, nullptr, 0, 0, nullptr, nullptr, N);
        prep_kernel<<<NBUK, 256, 0, stream>>>(gcur, bkt, elist, cnt, start, N, NBUK);
        fused_kernel<<<fb, 256, 0, stream>>>(x, elist, cnt, start, W, b, out, N);
    } else {
        float* counts = (float*)d_ws;
        int fb = (N + 31) / 32;
        hipMemsetAsync(d_out, 0, (size_t)N * D * sizeof(float), stream);
        hipMemsetAsync(d_ws, 0, (size_t)N * sizeof(float), stream);
        int sb = (E * 64 + 255) / 256;
        scatter_kernel<<<sb, 256, 0, stream>>>(x, eidx, out, counts, E);
        int db = (N * 64 + 255) / 256;
        divide_kernel<<<db, 256, 0, stream>>>(out, counts, N);
        gemm_kernel<<<fb, 256, 0, stream>>>(out, W, b, N);
    }
}